// Round 8
// baseline (429.043 us; speedup 1.0000x reference)
//
#include <hip/hip_runtime.h>

// Inputs: M (f32, 2048x4096), params (f32, 4096), kinds (int32, 4096).
// Output: f32, 10240x10240.
// Timing model: fixed harness overhead ~343 us/iter (1.6 GiB ws poison 267 +
// 400 MiB out poison ~65 + input restore ~11). Controllable floor: 419 MB
// write + ~34-67 MB read @ 6.36 TB/s ~= 71-76 us -> window floor ~414-419 us.
// History: R3 437.6 / R4 434.2 / R5 443.5 / R6 429.2 / R7 426.1.
// Fill counters prove ~3 waves/CU saturates write BW (Occ~10%, 79% peak).
#define NN 2048              // N_NODES
#define EE 4096              // N_ELEMS
#define WW 10240             // 2*E + N columns
#define TOT_ROWS 10240       // N + 2*E rows

typedef float v4f __attribute__((ext_vector_type(4)));

#define TP_BLOCKS 256        // 1024(M rows) x 32(M cols) tiles: 2 x 128

__device__ __forceinline__ void nt_store(float* p, v4f v) {
    __builtin_nontemporal_store(v, (v4f*)p);   // streamed, zero-reuse output
}

// Single fused kernel. Grid = [row blocks 0..10240) ++ [TP blocks ..+256).
//  Row blocks: one output ROW each, fully contiguous 32-40 KB stream:
//    rows [0,N):      [copy M row | zeros]  (16 KB contiguous copy chunk;
//                     also warms M into L2/L3 for the TP re-read)
//    rows [N,N+E):    [zeros | I_E]  cols [0,2E)  (-M^T owned by TP)
//    rows [N+E,2E+N): zeros + z@e + y@(E+e)
//  TP blocks (grid tail): 1024x32 M-tile in TWO 512-row LDS passes (same
//    64 KB LDS reused). Each output row receives two address-adjacent 2 KB
//    chunks from the same block close in time -> 4 KB DRAM page locality
//    (R7 had 2 KB), while M reads stay 128 B per M-row (unchanged).
// Every output element is written exactly once (out re-poisoned each call).
__global__ __launch_bounds__(256) void coeff_kernel(
    const float* __restrict__ M,
    const float* __restrict__ params,
    const int*   __restrict__ kinds,
    float*       __restrict__ out)
{
    int tid = threadIdx.x;

    if (blockIdx.x < TOT_ROWS) {
        int row = blockIdx.x;
        int tid4 = tid * 4;
        float* dst = out + (size_t)row * WW;
        const v4f zero = {0.f, 0.f, 0.f, 0.f};

        if (row < NN) {
            // [copy M row | zeros] — one contiguous 40 KB stream
            const float* src = M + (size_t)row * EE;
            #pragma unroll
            for (int k = 0; k < 4; ++k) {
                int off = k * 1024 + tid4;
                nt_store(dst + off, *(const v4f*)(src + off));
            }
            #pragma unroll
            for (int k = 4; k < 10; ++k)
                nt_store(dst + k * 1024 + tid4, zero);
        } else if (row < NN + EE) {
            // [zeros | I_E] over cols [0,2E)
            int e = row - NN;
            int col_y = EE + e;
            #pragma unroll
            for (int k = 0; k < 8; ++k) {
                int base = k * 1024 + tid4;
                v4f v = zero;
                #pragma unroll
                for (int j = 0; j < 4; ++j)
                    if (base + j == col_y) v[j] = 1.0f;
                nt_store(dst + base, v);
            }
        } else {
            // elem rows: z at col e, y at col E+e
            int e = row - (NN + EE);
            float p = params[e];
            int kk = kinds[e];
            bool on = p > 0.0f;
            float z, y;
            if (kk == 0)      { z = -p;             y = 1.0f; }           // R
            else if (kk == 1) { z = 0.0f;           y = 1.0f; }           // IVS
            else if (kk == 2) { z = 1.0f;           y = 0.0f; }           // VC
            else              { z = on ? 0.f : 1.f; y = on ? 1.f : 0.f; } // SW
            int col_z = e, col_y = EE + e;
            #pragma unroll
            for (int k = 0; k < 10; ++k) {
                int base = k * 1024 + tid4;
                v4f v = zero;
                #pragma unroll
                for (int j = 0; j < 4; ++j) {
                    if (base + j == col_z) v[j] = z;
                    if (base + j == col_y) v[j] = y;
                }
                nt_store(dst + base, v);
            }
        }
    } else {
        // TP tile: 1024 M-rows x 32 M-cols, two 512-row passes through the
        // same 64 KB LDS. Swizzle t[c*512 + (rr ^ (c&28))] (R7-verified):
        // scatter-writes <=2-way per bank; reads stay 16B-contiguous since
        // the XOR value is 4-aligned: (rr0 ^ (e&28)) + i for i in [0,4).
        __shared__ __align__(16) float t[32 * 512];   // 64 KB
        int tpIdx = blockIdx.x - TOT_ROWS;            // [0, 256)
        int cT = (tpIdx & 127) << 5;   // M col base (output row base), 128 tiles
        int rT = (tpIdx >> 7) << 10;   // M row base (output col base), 2 tiles

        #pragma unroll
        for (int p = 0; p < 2; ++p) {
            int rBase = rT + p * 512;

            #pragma unroll
            for (int it = 0; it < 16; ++it) {
                int rr = it * 32 + (tid >> 3);        // M row within pass
                int c0 = (tid & 7) * 4;               // M col within tile
                v4f val = *(const v4f*)(M + (size_t)(rBase + rr) * EE + cT + c0);
                #pragma unroll
                for (int i = 0; i < 4; ++i) {
                    int c = c0 + i;
                    t[c * 512 + (rr ^ (c & 28))] = val[i];
                }
            }
            __syncthreads();

            #pragma unroll
            for (int it = 0; it < 16; ++it) {
                int e   = it * 2 + (tid >> 7);        // output row within tile
                int rr0 = (tid & 127) * 4;            // output col within pass
                v4f v = *(const v4f*)(&t[e * 512 + (rr0 ^ (e & 28))]);
                v4f nv = { -v[0], -v[1], -v[2], -v[3] };
                nt_store(out + (size_t)(NN + cT + e) * WW + 2 * EE
                             + rBase + rr0, nv);
            }
            __syncthreads();   // protect LDS before next pass overwrites
        }
    }
}

extern "C" void kernel_launch(void* const* d_in, const int* in_sizes, int n_in,
                              void* d_out, int out_size, void* d_ws, size_t ws_size,
                              hipStream_t stream) {
    const float* M      = (const float*)d_in[0];   // f32, 2048x4096
    const float* params = (const float*)d_in[1];   // f32, 4096
    const int*   kinds  = (const int*)d_in[2];     // int32, 4096
    float*       out    = (float*)d_out;           // f32, 10240x10240

    coeff_kernel<<<TOT_ROWS + TP_BLOCKS, 256, 0, stream>>>(M, params, kinds, out);
}

// Round 9
// 426.161 us; speedup vs baseline: 1.0068x; 1.0068x over previous
//
#include <hip/hip_runtime.h>

// Inputs: M (f32, 2048x4096), params (f32, 4096), kinds (int32, 4096).
// Output: f32, 10240x10240.
// FINAL (R7 structure — measured optimum at 426.1 us window).
// Timing model: fixed harness overhead ~343 us/iter (1.6 GiB ws poison 267 +
// 400 MiB out poison ~65 + input restore ~11). Controllable floor: 419 MB
// write + ~34-67 MB read @ 6.36 TB/s ~= 71-76 us -> window floor ~414-419 us.
// History: R3 437.6 / R4 434.2 / R5 443.5 / R6 429.2 / R7 426.1 / R8 429.0
// (R8's 4KB 2-pass variant = noise/regression; chunk geometry exhausted).
#define NN 2048              // N_NODES
#define EE 4096              // N_ELEMS
#define WW 10240             // 2*E + N columns
#define TOT_ROWS 10240       // N + 2*E rows

typedef float v4f __attribute__((ext_vector_type(4)));

#define TP_BLOCKS 512        // 512(M rows) x 32(M cols) tiles: 4 x 128

__device__ __forceinline__ void nt_store(float* p, v4f v) {
    __builtin_nontemporal_store(v, (v4f*)p);   // streamed, zero-reuse output
}

// Single fused kernel. Grid = [row blocks 0..10240) ++ [TP blocks ..+512).
//  Row blocks: one output ROW each, fully contiguous 32-40 KB stream:
//    rows [0,N):      [copy M row | zeros]  (16 KB contiguous copy chunk;
//                     also warms M into L2/L3 for the TP re-read)
//    rows [N,N+E):    [zeros | I_E]  cols [0,2E)  (-M^T owned by TP)
//    rows [N+E,2E+N): zeros + z@e + y@(E+e)
//  TP blocks (grid tail -> run last, M re-read largely L3-resident):
//    512x32 tile of M -> -M^T rows [N,N+E), cols [2E,W); each output row
//    receives a 2 KB contiguous chunk. 64 KB LDS -> 2 blk/CU.
// Every output element is written exactly once (out re-poisoned each call).
__global__ __launch_bounds__(256) void coeff_kernel(
    const float* __restrict__ M,
    const float* __restrict__ params,
    const int*   __restrict__ kinds,
    float*       __restrict__ out)
{
    int tid = threadIdx.x;

    if (blockIdx.x < TOT_ROWS) {
        int row = blockIdx.x;
        int tid4 = tid * 4;
        float* dst = out + (size_t)row * WW;
        const v4f zero = {0.f, 0.f, 0.f, 0.f};

        if (row < NN) {
            // [copy M row | zeros] — one contiguous 40 KB stream
            const float* src = M + (size_t)row * EE;
            #pragma unroll
            for (int k = 0; k < 4; ++k) {
                int off = k * 1024 + tid4;
                nt_store(dst + off, *(const v4f*)(src + off));
            }
            #pragma unroll
            for (int k = 4; k < 10; ++k)
                nt_store(dst + k * 1024 + tid4, zero);
        } else if (row < NN + EE) {
            // [zeros | I_E] over cols [0,2E)
            int e = row - NN;
            int col_y = EE + e;
            #pragma unroll
            for (int k = 0; k < 8; ++k) {
                int base = k * 1024 + tid4;
                v4f v = zero;
                #pragma unroll
                for (int j = 0; j < 4; ++j)
                    if (base + j == col_y) v[j] = 1.0f;
                nt_store(dst + base, v);
            }
        } else {
            // elem rows: z at col e, y at col E+e
            int e = row - (NN + EE);
            float p = params[e];
            int kk = kinds[e];
            bool on = p > 0.0f;
            float z, y;
            if (kk == 0)      { z = -p;             y = 1.0f; }           // R
            else if (kk == 1) { z = 0.0f;           y = 1.0f; }           // IVS
            else if (kk == 2) { z = 1.0f;           y = 0.0f; }           // VC
            else              { z = on ? 0.f : 1.f; y = on ? 1.f : 0.f; } // SW
            int col_z = e, col_y = EE + e;
            #pragma unroll
            for (int k = 0; k < 10; ++k) {
                int base = k * 1024 + tid4;
                v4f v = zero;
                #pragma unroll
                for (int j = 0; j < 4; ++j) {
                    if (base + j == col_z) v[j] = z;
                    if (base + j == col_y) v[j] = y;
                }
                nt_store(dst + base, v);
            }
        }
    } else {
        // TP tile: 512 M-rows x 32 M-cols. LDS t[c][rr] with XOR swizzle
        // index c*512 + (rr ^ (c&28)):
        //  - write: 8 lanes sharing rr have distinct c&28 -> distinct banks;
        //    across a wave max 2-way aliasing (free per m136).
        //  - read: c fixed, (rr0+i)^(c&28) = (rr0^(c&28))+i for 4-aligned
        //    rr0 -> ds_read_b128 stays contiguous; uniform bank sweep.
        __shared__ __align__(16) float t[32 * 512];   // 64 KB
        int tpIdx = blockIdx.x - TOT_ROWS;            // [0, 512)
        int cT = (tpIdx & 127) << 5;   // M col base (output row base), 128 tiles
        int rT = (tpIdx >> 7) << 9;    // M row base (output col base), 4 tiles

        #pragma unroll
        for (int pass = 0; pass < 16; ++pass) {
            int rr = pass * 32 + (tid >> 3);          // M row within tile
            int c0 = (tid & 7) * 4;                   // M col within tile
            v4f val = *(const v4f*)(M + (size_t)(rT + rr) * EE + cT + c0);
            #pragma unroll
            for (int i = 0; i < 4; ++i) {
                int c = c0 + i;
                t[c * 512 + (rr ^ (c & 28))] = val[i];
            }
        }
        __syncthreads();

        #pragma unroll
        for (int pass = 0; pass < 16; ++pass) {
            int e   = pass * 2 + (tid >> 7);          // output row within tile
            int rr0 = (tid & 127) * 4;                // output col within tile
            v4f v = *(const v4f*)(&t[e * 512 + (rr0 ^ (e & 28))]);
            v4f nv = { -v[0], -v[1], -v[2], -v[3] };
            nt_store(out + (size_t)(NN + cT + e) * WW + 2 * EE + rT + rr0, nv);
        }
    }
}

extern "C" void kernel_launch(void* const* d_in, const int* in_sizes, int n_in,
                              void* d_out, int out_size, void* d_ws, size_t ws_size,
                              hipStream_t stream) {
    const float* M      = (const float*)d_in[0];   // f32, 2048x4096
    const float* params = (const float*)d_in[1];   // f32, 4096
    const int*   kinds  = (const int*)d_in[2];     // int32, 4096
    float*       out    = (float*)d_out;           // f32, 10240x10240

    coeff_kernel<<<TOT_ROWS + TP_BLOCKS, 256, 0, stream>>>(M, params, kinds, out);
}